// Round 17
// baseline (361.364 us; speedup 1.0000x reference)
//
#include <hip/hip_runtime.h>
#include <hip/hip_fp16.h>
#include <math.h>

#define NN 100000
#define EE 1600000
#define ETOT (EE + NN)
#define BN_EPS 1e-5f
#define NEG_SLOPE 0.2f
#define NBLK ((NN + 255) / 256)   // 391
#define NGRP 8
#define GRPSZ ((NN + NGRP - 1) / NGRP)   // 12500
#define HISTBLK 2048

typedef _Float16 half8 __attribute__((ext_vector_type(8)));
typedef float f32x4 __attribute__((ext_vector_type(4)));

// ---------- helpers ----------
__device__ __forceinline__ float lrelu(float x) { return fmaxf(x, NEG_SLOPE * x); }
__device__ __forceinline__ float wsum(float v) {
#pragma unroll
    for (int m = 32; m; m >>= 1) v += __shfl_xor(v, m, 64);
    return v;
}
__device__ __forceinline__ float gsum16(float v) {
#pragma unroll
    for (int m = 1; m < 16; m <<= 1) v += __shfl_xor(v, m, 64);
    return v;
}
__device__ __forceinline__ unsigned packh2(float a, float b) {
    __half2 p = __float22half2_rn(make_float2(a, b));
    return *reinterpret_cast<unsigned*>(&p);
}

// ========== prep (BN folds, w^T fp16, va/vd) + XCD-partitioned hist ==========
__global__ __launch_bounds__(256) void k_preph(
    const float* __restrict__ b1, const float* __restrict__ g1,
    const float* __restrict__ be1, const float* __restrict__ m1,
    const float* __restrict__ v1,
    const float* __restrict__ b2, const float* __restrict__ g2,
    const float* __restrict__ be2, const float* __restrict__ m2,
    const float* __restrict__ v2, const float* __restrict__ wc,
    const float* __restrict__ bc,
    const float* __restrict__ w1, const float* __restrict__ w2,
    const float* __restrict__ as1w, const float* __restrict__ ad1w,
    const int* __restrict__ ei,
    float* __restrict__ scs, float* __restrict__ shs,
    float* __restrict__ wq, float* __restrict__ cst,
    float* __restrict__ va, float* __restrict__ vd,
    _Float16* __restrict__ wt1, _Float16* __restrict__ wt2,
    int* __restrict__ counts)
{
    const int b = blockIdx.x, t = threadIdx.x;
    if (b == 0) {
        const float sc = g1[t] * rsqrtf(v1[t] + BN_EPS);
        scs[t] = sc;
        shs[t] = (b1[t] - m1[t]) * sc + be1[t];
    } else if (b == 1) {
        if (t < 64) {
            const float s2 = g2[t] * rsqrtf(v2[t] + BN_EPS);
            wq[t * 2 + 0] = s2 * wc[t * 2 + 0];
            wq[t * 2 + 1] = s2 * wc[t * 2 + 1];
            const float tv = (b2[t] - m2[t]) * s2 + be2[t];
            const float c0 = wsum(tv * wc[t * 2 + 0]);
            const float c1 = wsum(tv * wc[t * 2 + 1]);
            if (t == 0) { cst[0] = c0 + bc[0]; cst[1] = c1 + bc[1]; }
        }
    } else if (b < 130) {
        const int idx = (b - 2) * 256 + t;           // wt1[n][k] = w1[k][n]
        const int n = idx >> 7, k = idx & 127;
        wt1[idx] = (_Float16)w1[k * 256 + n];
    } else if (b < 258) {
        const int idx = (b - 130) * 256 + t;         // wt2[n][k] = w2[k][n]
        const int n = idx >> 8, k = idx & 255;
        wt2[idx] = (_Float16)w2[k * 128 + n];
    } else if (b == 258) {
#pragma unroll
        for (int rep = 0; rep < 2; ++rep) {
            const int idx = rep * 256 + t;           // 0..511 = h*128+k
            const int h = idx >> 7, k = idx & 127;
            float sa = 0.f, sd = 0.f;
            for (int c = 0; c < 64; ++c) {
                const float wv = w1[k * 256 + h * 64 + c];
                sa = fmaf(wv, as1w[h * 64 + c], sa);
                sd = fmaf(wv, ad1w[h * 64 + c], sd);
            }
            va[idx] = sa;
            vd[idx] = sd;
        }
    } else {
        // XCD-partitioned histogram (counts pre-zeroed by memsetAsync)
        const int bh = b - 259;
        const int g = bh & (NGRP - 1);
        const int lo = g * GRPSZ;
        const int hi = (lo + GRPSZ < NN) ? lo + GRPSZ : NN;
        const int stride = (HISTBLK >> 3) * 256;
        for (int e = (bh >> 3) * 256 + t; e < EE; e += stride) {
            const int d = ei[EE + e];
            if (d >= lo && d < hi) atomicAdd(&counts[d], 1);
        }
    }
}

// ================= CSR scans =================
__global__ __launch_bounds__(256) void k_scan_bsum(const int* __restrict__ counts,
                                                   int* __restrict__ bsum) {
    __shared__ int sd[256];
    const int i = blockIdx.x * 256 + threadIdx.x;
    sd[threadIdx.x] = (i < NN) ? counts[i] + 1 : 0;   // +1 = self-loop
    __syncthreads();
    for (int s2 = 128; s2; s2 >>= 1) {
        if (threadIdx.x < s2) sd[threadIdx.x] += sd[threadIdx.x + s2];
        __syncthreads();
    }
    if (threadIdx.x == 0) bsum[blockIdx.x] = sd[0];
}
__global__ __launch_bounds__(256) void k_scan_finaltop(
    const int* __restrict__ counts, const int* __restrict__ bsum,
    int* __restrict__ rowptr, int* __restrict__ srcs, int* __restrict__ cursor)
{
    __shared__ int sd[256];
    int partial = 0;
    for (int j = threadIdx.x; j < NBLK; j += 256)
        if (j < blockIdx.x) partial += bsum[j];
    sd[threadIdx.x] = partial;
    __syncthreads();
    for (int s2 = 128; s2; s2 >>= 1) {
        if (threadIdx.x < s2) sd[threadIdx.x] += sd[threadIdx.x + s2];
        __syncthreads();
    }
    const int base = sd[0];
    __syncthreads();
    const int i = blockIdx.x * 256 + threadIdx.x;
    const int orig = (i < NN) ? counts[i] + 1 : 0;
    sd[threadIdx.x] = orig;
    __syncthreads();
    for (int off = 1; off < 256; off <<= 1) {
        const int v = (threadIdx.x >= off) ? sd[threadIdx.x - off] : 0;
        __syncthreads();
        sd[threadIdx.x] += v;
        __syncthreads();
    }
    if (i < NN) {
        const int rp = base + sd[threadIdx.x] - orig;
        rowptr[i] = rp;
        srcs[rp] = i;                                // self-loop first
        cursor[i] = rp + 1;
        if (i == NN - 1) rowptr[NN] = ETOT;
    }
}
__global__ __launch_bounds__(256) void k_scatter8(const int* __restrict__ ei,
                                                  int* __restrict__ srcs,
                                                  int* __restrict__ cursor) {
    const int g = blockIdx.x & (NGRP - 1);
    const int lo = g * GRPSZ;
    const int hi = (lo + GRPSZ < NN) ? lo + GRPSZ : NN;
    const int nb = gridDim.x >> 3;
    const int stride = nb * 256;
    for (int e = (blockIdx.x >> 3) * 256 + threadIdx.x; e < EE; e += stride) {
        const int d = ei[EE + e];
        if (d >= lo && d < hi) {
            const int p = atomicAdd(&cursor[d], 1);
            srcs[p] = ei[e];
        }
    }
}

// ====== x -> fp16, + as1/ad1 = x·va / x·vd (16 lanes per node) ======
__global__ __launch_bounds__(256) void k_xcvt(
    const float* __restrict__ x, const float* __restrict__ va,
    const float* __restrict__ vd, _Float16* __restrict__ xh,
    float* __restrict__ as_, float* __restrict__ ad_)
{
    const int gid = blockIdx.x * 256 + threadIdx.x;
    const int n = gid >> 4;
    if (n >= NN) return;
    const int j = gid & 15;
    const int k0 = j * 8;
    float xv[8];
    *(float4*)&xv[0] = *(const float4*)&x[(unsigned)n * 128u + k0];
    *(float4*)&xv[4] = *(const float4*)&x[(unsigned)n * 128u + k0 + 4];
    half8 hv;
#pragma unroll
    for (int i = 0; i < 8; ++i) hv[i] = (_Float16)xv[i];
    *(half8*)&xh[(unsigned)n * 128u + k0] = hv;
    float sa[4], sd[4];
#pragma unroll
    for (int h = 0; h < 4; ++h) {
        float s = 0.f, d = 0.f;
#pragma unroll
        for (int i = 0; i < 8; ++i) {
            s = fmaf(xv[i], va[h * 128 + k0 + i], s);
            d = fmaf(xv[i], vd[h * 128 + k0 + i], d);
        }
        sa[h] = gsum16(s);
        sd[h] = gsum16(d);
    }
    if (j == 0) {
        *(float4*)&as_[n * 4] = make_float4(sa[0], sa[1], sa[2], sa[3]);
        *(float4*)&ad_[n * 4] = make_float4(sd[0], sd[1], sd[2], sd[3]);
    }
}

// ====== layer-1 aggregation over x; shfl p-sharing (R13 form, 32-bit indexing) =====
__global__ __launch_bounds__(256) void k_agg1x(
    const int* __restrict__ rowptr, const int* __restrict__ srcs,
    const _Float16* __restrict__ xh, const float* __restrict__ as_,
    const float* __restrict__ ad_, _Float16* __restrict__ y)
{
    const int d = blockIdx.x * 4 + (threadIdx.x >> 6);
    if (d >= NN) return;
    const int lane = threadIdx.x & 63;
    const int r0 = rowptr[d], r1 = rowptr[d + 1];
    const int h = lane >> 4;
    const unsigned cb = (lane & 15) * 8;
    const float myad = ad_[d * 4 + h];

    float den = 0.f;
    float acc[8] = {0.f, 0.f, 0.f, 0.f, 0.f, 0.f, 0.f, 0.f};
    int k = r0;
    for (; k + 3 < r1; k += 4) {
        // one p per lane: edge k+(lane&3), head lane>>4; share via shfl
        const int sm = srcs[k + (lane & 3)];
        const float pm = __expf(lrelu(as_[(unsigned)sm * 4u + h] + myad));
        const int s0 = __shfl(sm, 0, 64);
        const int s1 = __shfl(sm, 1, 64);
        const int s2 = __shfl(sm, 2, 64);
        const int s3 = __shfl(sm, 3, 64);
        const int pb = lane & 48;
        const float p0 = __shfl(pm, pb | 0, 64);
        const float p1 = __shfl(pm, pb | 1, 64);
        const float p2 = __shfl(pm, pb | 2, 64);
        const float p3 = __shfl(pm, pb | 3, 64);
        den += (p0 + p1) + (p2 + p3);
        const half8 v0 = *(const half8*)&xh[(unsigned)s0 * 128u + cb];
        const half8 v1 = *(const half8*)&xh[(unsigned)s1 * 128u + cb];
        const half8 v2 = *(const half8*)&xh[(unsigned)s2 * 128u + cb];
        const half8 v3 = *(const half8*)&xh[(unsigned)s3 * 128u + cb];
#pragma unroll
        for (int i = 0; i < 8; ++i) {
            acc[i] = fmaf(p0, (float)v0[i], acc[i]);
            acc[i] = fmaf(p1, (float)v1[i], acc[i]);
            acc[i] = fmaf(p2, (float)v2[i], acc[i]);
            acc[i] = fmaf(p3, (float)v3[i], acc[i]);
        }
    }
    for (; k < r1; ++k) {
        const int s = srcs[k];
        const float p = __expf(lrelu(as_[(unsigned)s * 4u + h] + myad));
        den += p;
        const half8 v = *(const half8*)&xh[(unsigned)s * 128u + cb];
#pragma unroll
        for (int i = 0; i < 8; ++i) acc[i] = fmaf(p, (float)v[i], acc[i]);
    }
    const float inv = 1.f / (den + 1e-16f);
    half8 hv;
#pragma unroll
    for (int i = 0; i < 8; ++i) hv[i] = (_Float16)(acc[i] * inv);
    *(half8*)&y[(unsigned)d * 512u + (unsigned)h * 128u + cb] = hv;
}

// ====== fused: per-head BD-GEMM (y@W1_h, BN1+ELU) -> mid(LDS) -> GEMM2 -> pack ======
// 64-row tiles; grid ceil(NN/64); 4 waves.
__global__ __launch_bounds__(256) void k_l2fuse(
    const _Float16* __restrict__ y,    // [NN][4][128]
    const _Float16* __restrict__ wt1,  // [256][128]
    const _Float16* __restrict__ wt2,  // [128][256]
    const float* __restrict__ scs, const float* __restrict__ shs,
    const float* __restrict__ asrc, const float* __restrict__ adst,
    const float* __restrict__ wq,
    float* __restrict__ ad_, uint2* __restrict__ pack)
{
    __shared__ _Float16 ys[64][136];
    __shared__ _Float16 mid[64][264];
    const int n0 = blockIdx.x * 64;
    const int t = threadIdx.x;
    const int l = t & 63, w = t >> 6;
    const int lc = l & 15, kq = (l >> 4) * 8, lr = (l >> 4) * 4;
    const int m0w = (w & 1) * 32;          // 2 row-tiles per wave
    const f32x4 fzero = {0.f, 0.f, 0.f, 0.f};

    // ---- phase 1: per head, mid[:, h*64..] = ELU(BN1(y_h @ W1_h)) ----
    const int c0w = (w >> 1) * 32;         // 2 col-tiles per wave (within head)
    for (int h = 0; h < 4; ++h) {
        if (h) __syncthreads();
#pragma unroll
        for (int i = 0; i < 4; ++i) {
            const int f = i * 2048 + t * 8;
            const int m = f >> 7, k8 = f & 127;
            half8 v = {};
            if (n0 + m < NN)
                v = *(const half8*)&y[(unsigned)(n0 + m) * 512u + (unsigned)h * 128u + k8];
            *(half8*)&ys[m][k8] = v;
        }
        __syncthreads();

        f32x4 acc[2][2];
        acc[0][0] = fzero; acc[0][1] = fzero; acc[1][0] = fzero; acc[1][1] = fzero;
#pragma unroll
        for (int ks = 0; ks < 4; ++ks) {
            const int k0 = ks * 32 + kq;
            const half8 a0 = *(const half8*)&ys[m0w + lc][k0];
            const half8 a1 = *(const half8*)&ys[m0w + 16 + lc][k0];
            const half8 b0 = *(const half8*)&wt1[(unsigned)(h * 64 + c0w + lc) * 128u + k0];
            const half8 b1 = *(const half8*)&wt1[(unsigned)(h * 64 + c0w + 16 + lc) * 128u + k0];
            acc[0][0] = __builtin_amdgcn_mfma_f32_16x16x32_f16(a0, b0, acc[0][0], 0, 0, 0);
            acc[0][1] = __builtin_amdgcn_mfma_f32_16x16x32_f16(a0, b1, acc[0][1], 0, 0, 0);
            acc[1][0] = __builtin_amdgcn_mfma_f32_16x16x32_f16(a1, b0, acc[1][0], 0, 0, 0);
            acc[1][1] = __builtin_amdgcn_mfma_f32_16x16x32_f16(a1, b1, acc[1][1], 0, 0, 0);
        }
        // BN1 + ELU -> mid
#pragma unroll
        for (int c = 0; c < 2; ++c) {
            const int col = h * 64 + c0w + c * 16 + lc;
            const float scv = scs[col], shv = shs[col];
#pragma unroll
            for (int r = 0; r < 2; ++r) {
#pragma unroll
                for (int i = 0; i < 4; ++i) {
                    float e = fmaf(acc[r][c][i], scv, shv);
                    e = e > 0.f ? e : __expf(e) - 1.f;
                    mid[m0w + r * 16 + lr + i][col] = (_Float16)e;
                }
            }
        }
    }
    __syncthreads();

    // ---- phase 2: gemm2 K=256 from mid; wave head = w>>1, cols c20..c20+63 ----
    const int c20 = (w >> 1) * 64;
    f32x4 acc2[2][4];
#pragma unroll
    for (int r = 0; r < 2; ++r)
#pragma unroll
        for (int c = 0; c < 4; ++c) acc2[r][c] = fzero;
#pragma unroll
    for (int ks = 0; ks < 8; ++ks) {
        const int k0 = ks * 32 + kq;
        const half8 a0 = *(const half8*)&mid[m0w + lc][k0];
        const half8 a1 = *(const half8*)&mid[m0w + 16 + lc][k0];
#pragma unroll
        for (int c = 0; c < 4; ++c) {
            const half8 b = *(const half8*)&wt2[(unsigned)(c20 + c * 16 + lc) * 256u + k0];
            acc2[0][c] = __builtin_amdgcn_mfma_f32_16x16x32_f16(a0, b, acc2[0][c], 0, 0, 0);
            acc2[1][c] = __builtin_amdgcn_mfma_f32_16x16x32_f16(a1, b, acc2[1][c], 0, 0, 0);
        }
    }
    const int head = w >> 1;
    float awv[4], dwv[4], wq0[4], wq1[4];
#pragma unroll
    for (int c = 0; c < 4; ++c) {
        const int j = c20 + c * 16 + lc;
        const int cl = j & 63;
        awv[c] = asrc[j];
        dwv[c] = adst[j];
        wq0[c] = wq[cl * 2 + 0];
        wq1[c] = wq[cl * 2 + 1];
    }
#pragma unroll
    for (int r = 0; r < 2; ++r) {
#pragma unroll
        for (int i = 0; i < 4; ++i) {
            float s = 0.f, d = 0.f, q0 = 0.f, q1 = 0.f;
#pragma unroll
            for (int c = 0; c < 4; ++c) {
                s = fmaf(acc2[r][c][i], awv[c], s);
                d = fmaf(acc2[r][c][i], dwv[c], d);
                q0 = fmaf(acc2[r][c][i], wq0[c], q0);
                q1 = fmaf(acc2[r][c][i], wq1[c], q1);
            }
            s = gsum16(s); d = gsum16(d); q0 = gsum16(q0); q1 = gsum16(q1);
            const int rg = n0 + m0w + r * 16 + lr + i;
            if (lc == 0 && rg < NN) {
                ad_[rg * 2 + head] = d;
                uint2 u;
                u.x = __float_as_uint(s);
                u.y = packh2(q0, q1);
                pack[rg * 2 + head] = u;
            }
        }
    }
}

// ====== layer-2: single-pass softmax; one 16B record gather per edge ======
__global__ __launch_bounds__(256) void k_agg2q(
    const int* __restrict__ rowptr, const int* __restrict__ srcs,
    const uint4* __restrict__ pack, const float* __restrict__ ad_,
    const float* __restrict__ cst, float* __restrict__ out)
{
    const int d = blockIdx.x * 16 + (threadIdx.x >> 4);
    if (d >= NN) return;
    const int il = threadIdx.x & 15;
    const int r0 = rowptr[d], r1 = rowptr[d + 1];
    const float2 adv = *(const float2*)&ad_[d * 2];

    float den0 = 0.f, den1 = 0.f;
    float qa00 = 0.f, qa01 = 0.f, qa10 = 0.f, qa11 = 0.f;
    for (int k = r0 + il; k < r1; k += 16) {
        const unsigned s = (unsigned)srcs[k];
        const uint4 rec = pack[s];
        const float a0 = __uint_as_float(rec.x);
        const float a1 = __uint_as_float(rec.z);
        const float2 q0 = __half22float2(*reinterpret_cast<const __half2*>(&rec.y));
        const float2 q1 = __half22float2(*reinterpret_cast<const __half2*>(&rec.w));
        const float p0 = __expf(lrelu(a0 + adv.x));
        const float p1 = __expf(lrelu(a1 + adv.y));
        den0 += p0; den1 += p1;
        qa00 = fmaf(p0, q0.x, qa00); qa01 = fmaf(p0, q0.y, qa01);
        qa10 = fmaf(p1, q1.x, qa10); qa11 = fmaf(p1, q1.y, qa11);
    }
    den0 = gsum16(den0); den1 = gsum16(den1);
    qa00 = gsum16(qa00); qa01 = gsum16(qa01);
    qa10 = gsum16(qa10); qa11 = gsum16(qa11);
    if (il == 0) {
        const float i0 = 1.f / (den0 + 1e-16f);
        const float i1 = 1.f / (den1 + 1e-16f);
        out[d * 2 + 0] = cst[0] + 0.5f * (qa00 * i0 + qa10 * i1);
        out[d * 2 + 1] = cst[1] + 0.5f * (qa01 * i0 + qa11 * i1);
    }
}

extern "C" void kernel_launch(void* const* d_in, const int* in_sizes, int n_in,
                              void* d_out, int out_size, void* d_ws, size_t ws_size,
                              hipStream_t stream) {
    const float* x      = (const float*)d_in[0];
    const int*   ei     = (const int*)d_in[1];
    const float* w1     = (const float*)d_in[2];
    const float* a_src1 = (const float*)d_in[3];
    const float* a_dst1 = (const float*)d_in[4];
    const float* b1     = (const float*)d_in[5];
    const float* g1     = (const float*)d_in[6];
    const float* be1    = (const float*)d_in[7];
    const float* m1     = (const float*)d_in[8];
    const float* v1     = (const float*)d_in[9];
    const float* w2     = (const float*)d_in[10];
    const float* a_src2 = (const float*)d_in[11];
    const float* a_dst2 = (const float*)d_in[12];
    const float* b2     = (const float*)d_in[13];
    const float* g2     = (const float*)d_in[14];
    const float* be2    = (const float*)d_in[15];
    const float* m2     = (const float*)d_in[16];
    const float* v2     = (const float*)d_in[17];
    const float* wc     = (const float*)d_in[18];
    const float* bc     = (const float*)d_in[19];
    float* out = (float*)d_out;

    float* ws = (float*)d_ws;
    _Float16* xh = (_Float16*)ws;                      // NN*128 h  (NN*64 fl)
    _Float16* y  = (_Float16*)(ws + (size_t)NN * 64);  // NN*512 h  (NN*256 fl)
    float* C = ws + (size_t)NN * 320;

    float* as1 = C;                        // NN*4
    float* ad1 = C + (size_t)NN * 4;       // NN*4
    float* ad2 = C + (size_t)NN * 8;       // NN*2
    float* packf = C + (size_t)NN * 10;    // NN*4 (uint2 x2 per node)
    float* scs = C + (size_t)NN * 14;      // 256
    float* shs = scs + 256;                // 256
    float* wq  = shs + 256;                // 128
    float* cst = wq + 128;                 // 64
    float* va  = cst + 64;                 // 512
    float* vd  = va + 512;                 // 512
    float* wbase = vd + 512;
    _Float16* wt1 = (_Float16*)wbase;      // 32768 h (16384 fl)
    _Float16* wt2 = wt1 + 32768;           // 32768 h
    int* counts = (int*)(wbase + 32768);   // NN (reused as cursor)
    int* rowptr = counts + NN;             // NN+1
    int* bsum   = rowptr + NN + 63;        // 512
    int* srcs   = bsum + 512;              // ETOT

    // ---- counts zero + combined prep/hist ----
    hipMemsetAsync(counts, 0, (size_t)NN * sizeof(int), stream);
    k_preph<<<259 + HISTBLK, 256, 0, stream>>>(
        b1, g1, be1, m1, v1, b2, g2, be2, m2, v2, wc, bc, w1, w2,
        a_src1, a_dst1, ei, scs, shs, wq, cst, va, vd, wt1, wt2, counts);

    // ---- CSR scans + scatter ----
    k_scan_bsum<<<NBLK, 256, 0, stream>>>(counts, bsum);
    k_scan_finaltop<<<NBLK, 256, 0, stream>>>(counts, bsum, rowptr, srcs, counts);
    k_scatter8<<<2048, 256, 0, stream>>>(ei, srcs, counts);

    // ---- layer 1 ----
    k_xcvt<<<(NN * 16 + 255) / 256, 256, 0, stream>>>(x, va, vd, xh, as1, ad1);
    k_agg1x<<<(NN + 3) / 4, 256, 0, stream>>>(rowptr, srcs, xh, as1, ad1, y);

    // ---- fused BD-GEMM + GEMM2 ----
    k_l2fuse<<<(NN + 63) / 64, 256, 0, stream>>>(y, wt1, wt2, scs, shs,
                                                 a_src2, a_dst2, wq,
                                                 ad2, (uint2*)packf);

    // ---- layer 2 edge pass ----
    k_agg2q<<<(NN + 15) / 16, 256, 0, stream>>>(rowptr, srcs, (const uint4*)packf,
                                                ad2, cst, out);
}

// Round 18
// 349.168 us; speedup vs baseline: 1.0349x; 1.0349x over previous
//
#include <hip/hip_runtime.h>
#include <hip/hip_fp16.h>
#include <math.h>

#define NN 100000
#define EE 1600000
#define ETOT (EE + NN)
#define BN_EPS 1e-5f
#define NEG_SLOPE 0.2f
#define NBLK ((NN + 255) / 256)   // 391
#define NGRP 8
#define GRPSZ ((NN + NGRP - 1) / NGRP)   // 12500
#define HISTBLK 2048
#define SCTBLK 2048
#define XCVTBLK ((NN * 16 + 255) / 256)  // 6250

typedef _Float16 half8 __attribute__((ext_vector_type(8)));
typedef float f32x4 __attribute__((ext_vector_type(4)));

// ---------- helpers ----------
__device__ __forceinline__ float lrelu(float x) { return fmaxf(x, NEG_SLOPE * x); }
__device__ __forceinline__ float wsum(float v) {
#pragma unroll
    for (int m = 32; m; m >>= 1) v += __shfl_xor(v, m, 64);
    return v;
}
__device__ __forceinline__ float gsum16(float v) {
#pragma unroll
    for (int m = 1; m < 16; m <<= 1) v += __shfl_xor(v, m, 64);
    return v;
}
__device__ __forceinline__ unsigned packh2(float a, float b) {
    __half2 p = __float22half2_rn(make_float2(a, b));
    return *reinterpret_cast<unsigned*>(&p);
}

// ========== prep (BN folds, w^T fp16, va/vd) + XCD-partitioned hist ==========
__global__ __launch_bounds__(256) void k_preph(
    const float* __restrict__ b1, const float* __restrict__ g1,
    const float* __restrict__ be1, const float* __restrict__ m1,
    const float* __restrict__ v1,
    const float* __restrict__ b2, const float* __restrict__ g2,
    const float* __restrict__ be2, const float* __restrict__ m2,
    const float* __restrict__ v2, const float* __restrict__ wc,
    const float* __restrict__ bc,
    const float* __restrict__ w1, const float* __restrict__ w2,
    const float* __restrict__ as1w, const float* __restrict__ ad1w,
    const int* __restrict__ ei,
    float* __restrict__ scs, float* __restrict__ shs,
    float* __restrict__ wq, float* __restrict__ cst,
    float* __restrict__ va, float* __restrict__ vd,
    _Float16* __restrict__ wt1, _Float16* __restrict__ wt2,
    int* __restrict__ counts)
{
    const int b = blockIdx.x, t = threadIdx.x;
    if (b == 0) {
        const float sc = g1[t] * rsqrtf(v1[t] + BN_EPS);
        scs[t] = sc;
        shs[t] = (b1[t] - m1[t]) * sc + be1[t];
    } else if (b == 1) {
        if (t < 64) {
            const float s2 = g2[t] * rsqrtf(v2[t] + BN_EPS);
            wq[t * 2 + 0] = s2 * wc[t * 2 + 0];
            wq[t * 2 + 1] = s2 * wc[t * 2 + 1];
            const float tv = (b2[t] - m2[t]) * s2 + be2[t];
            const float c0 = wsum(tv * wc[t * 2 + 0]);
            const float c1 = wsum(tv * wc[t * 2 + 1]);
            if (t == 0) { cst[0] = c0 + bc[0]; cst[1] = c1 + bc[1]; }
        }
    } else if (b < 130) {
        const int idx = (b - 2) * 256 + t;           // wt1[n][k] = w1[k][n]
        const int n = idx >> 7, k = idx & 127;
        wt1[idx] = (_Float16)w1[k * 256 + n];
    } else if (b < 258) {
        const int idx = (b - 130) * 256 + t;         // wt2[n][k] = w2[k][n]
        const int n = idx >> 8, k = idx & 255;
        wt2[idx] = (_Float16)w2[k * 128 + n];
    } else if (b == 258) {
#pragma unroll
        for (int rep = 0; rep < 2; ++rep) {
            const int idx = rep * 256 + t;           // 0..511 = h*128+k
            const int h = idx >> 7, k = idx & 127;
            float sa = 0.f, sd = 0.f;
            for (int c = 0; c < 64; ++c) {
                const float wv = w1[k * 256 + h * 64 + c];
                sa = fmaf(wv, as1w[h * 64 + c], sa);
                sd = fmaf(wv, ad1w[h * 64 + c], sd);
            }
            va[idx] = sa;
            vd[idx] = sd;
        }
    } else {
        // XCD-partitioned histogram (counts pre-zeroed by memsetAsync)
        const int bh = b - 259;
        const int g = bh & (NGRP - 1);
        const int lo = g * GRPSZ;
        const int hi = (lo + GRPSZ < NN) ? lo + GRPSZ : NN;
        const int stride = (HISTBLK >> 3) * 256;
        for (int e = (bh >> 3) * 256 + t; e < EE; e += stride) {
            const int d = ei[EE + e];
            if (d >= lo && d < hi) atomicAdd(&counts[d], 1);
        }
    }
}

// ================= CSR scans =================
__global__ __launch_bounds__(256) void k_scan_bsum(const int* __restrict__ counts,
                                                   int* __restrict__ bsum) {
    __shared__ int sd[256];
    const int i = blockIdx.x * 256 + threadIdx.x;
    sd[threadIdx.x] = (i < NN) ? counts[i] + 1 : 0;   // +1 = self-loop
    __syncthreads();
    for (int s2 = 128; s2; s2 >>= 1) {
        if (threadIdx.x < s2) sd[threadIdx.x] += sd[threadIdx.x + s2];
        __syncthreads();
    }
    if (threadIdx.x == 0) bsum[blockIdx.x] = sd[0];
}
__global__ __launch_bounds__(256) void k_scan_finaltop(
    const int* __restrict__ counts, const int* __restrict__ bsum,
    int* __restrict__ rowptr, int* __restrict__ srcs, int* __restrict__ cursor)
{
    __shared__ int sd[256];
    int partial = 0;
    for (int j = threadIdx.x; j < NBLK; j += 256)
        if (j < blockIdx.x) partial += bsum[j];
    sd[threadIdx.x] = partial;
    __syncthreads();
    for (int s2 = 128; s2; s2 >>= 1) {
        if (threadIdx.x < s2) sd[threadIdx.x] += sd[threadIdx.x + s2];
        __syncthreads();
    }
    const int base = sd[0];
    __syncthreads();
    const int i = blockIdx.x * 256 + threadIdx.x;
    const int orig = (i < NN) ? counts[i] + 1 : 0;
    sd[threadIdx.x] = orig;
    __syncthreads();
    for (int off = 1; off < 256; off <<= 1) {
        const int v = (threadIdx.x >= off) ? sd[threadIdx.x - off] : 0;
        __syncthreads();
        sd[threadIdx.x] += v;
        __syncthreads();
    }
    if (i < NN) {
        const int rp = base + sd[threadIdx.x] - orig;
        rowptr[i] = rp;
        srcs[rp] = i;                                // self-loop first
        cursor[i] = rp + 1;
        if (i == NN - 1) rowptr[NN] = ETOT;
    }
}

// ====== merged: XCD-partitioned scatter (blocks 0..2047) + x->fp16/coef (rest) =====
__global__ __launch_bounds__(256) void k_scx(
    const int* __restrict__ ei, int* __restrict__ srcs, int* __restrict__ cursor,
    const float* __restrict__ x, const float* __restrict__ va,
    const float* __restrict__ vd, _Float16* __restrict__ xh,
    float* __restrict__ as_, float* __restrict__ ad_)
{
    const int b = blockIdx.x;
    if (b < SCTBLK) {
        const int g = b & (NGRP - 1);
        const int lo = g * GRPSZ;
        const int hi = (lo + GRPSZ < NN) ? lo + GRPSZ : NN;
        const int stride = (SCTBLK >> 3) * 256;
        for (int e = (b >> 3) * 256 + threadIdx.x; e < EE; e += stride) {
            const int d = ei[EE + e];
            if (d >= lo && d < hi) {
                const int p = atomicAdd(&cursor[d], 1);
                srcs[p] = ei[e];
            }
        }
        return;
    }
    const int gid = (b - SCTBLK) * 256 + threadIdx.x;
    const int n = gid >> 4;
    if (n >= NN) return;
    const int j = gid & 15;
    const int k0 = j * 8;
    float xv[8];
    *(float4*)&xv[0] = *(const float4*)&x[(unsigned)n * 128u + k0];
    *(float4*)&xv[4] = *(const float4*)&x[(unsigned)n * 128u + k0 + 4];
    half8 hv;
#pragma unroll
    for (int i = 0; i < 8; ++i) hv[i] = (_Float16)xv[i];
    *(half8*)&xh[(unsigned)n * 128u + k0] = hv;
    float sa[4], sd[4];
#pragma unroll
    for (int h = 0; h < 4; ++h) {
        float s = 0.f, d = 0.f;
#pragma unroll
        for (int i = 0; i < 8; ++i) {
            s = fmaf(xv[i], va[h * 128 + k0 + i], s);
            d = fmaf(xv[i], vd[h * 128 + k0 + i], d);
        }
        sa[h] = gsum16(s);
        sd[h] = gsum16(d);
    }
    if (j == 0) {
        *(float4*)&as_[n * 4] = make_float4(sa[0], sa[1], sa[2], sa[3]);
        *(float4*)&ad_[n * 4] = make_float4(sd[0], sd[1], sd[2], sd[3]);
    }
}

// ====== layer-1 aggregation over x; shfl p-sharing (R13 form, 32-bit indexing) =====
__global__ __launch_bounds__(256) void k_agg1x(
    const int* __restrict__ rowptr, const int* __restrict__ srcs,
    const _Float16* __restrict__ xh, const float* __restrict__ as_,
    const float* __restrict__ ad_, _Float16* __restrict__ y)
{
    const int d = blockIdx.x * 4 + (threadIdx.x >> 6);
    if (d >= NN) return;
    const int lane = threadIdx.x & 63;
    const int r0 = rowptr[d], r1 = rowptr[d + 1];
    const int h = lane >> 4;
    const unsigned cb = (lane & 15) * 8;
    const float myad = ad_[d * 4 + h];

    float den = 0.f;
    float acc[8] = {0.f, 0.f, 0.f, 0.f, 0.f, 0.f, 0.f, 0.f};
    int k = r0;
    for (; k + 3 < r1; k += 4) {
        const int sm = srcs[k + (lane & 3)];
        const float pm = __expf(lrelu(as_[(unsigned)sm * 4u + h] + myad));
        const int s0 = __shfl(sm, 0, 64);
        const int s1 = __shfl(sm, 1, 64);
        const int s2 = __shfl(sm, 2, 64);
        const int s3 = __shfl(sm, 3, 64);
        const int pb = lane & 48;
        const float p0 = __shfl(pm, pb | 0, 64);
        const float p1 = __shfl(pm, pb | 1, 64);
        const float p2 = __shfl(pm, pb | 2, 64);
        const float p3 = __shfl(pm, pb | 3, 64);
        den += (p0 + p1) + (p2 + p3);
        const half8 v0 = *(const half8*)&xh[(unsigned)s0 * 128u + cb];
        const half8 v1 = *(const half8*)&xh[(unsigned)s1 * 128u + cb];
        const half8 v2 = *(const half8*)&xh[(unsigned)s2 * 128u + cb];
        const half8 v3 = *(const half8*)&xh[(unsigned)s3 * 128u + cb];
#pragma unroll
        for (int i = 0; i < 8; ++i) {
            acc[i] = fmaf(p0, (float)v0[i], acc[i]);
            acc[i] = fmaf(p1, (float)v1[i], acc[i]);
            acc[i] = fmaf(p2, (float)v2[i], acc[i]);
            acc[i] = fmaf(p3, (float)v3[i], acc[i]);
        }
    }
    for (; k < r1; ++k) {
        const int s = srcs[k];
        const float p = __expf(lrelu(as_[(unsigned)s * 4u + h] + myad));
        den += p;
        const half8 v = *(const half8*)&xh[(unsigned)s * 128u + cb];
#pragma unroll
        for (int i = 0; i < 8; ++i) acc[i] = fmaf(p, (float)v[i], acc[i]);
    }
    const float inv = 1.f / (den + 1e-16f);
    half8 hv;
#pragma unroll
    for (int i = 0; i < 8; ++i) hv[i] = (_Float16)(acc[i] * inv);
    *(half8*)&y[(unsigned)d * 512u + (unsigned)h * 128u + cb] = hv;
}

// ====== fused: per-head BD-GEMM (y@W1_h, BN1+ELU) -> mid(LDS) -> GEMM2 -> pack ======
__global__ __launch_bounds__(256) void k_l2fuse(
    const _Float16* __restrict__ y,    // [NN][4][128]
    const _Float16* __restrict__ wt1,  // [256][128]
    const _Float16* __restrict__ wt2,  // [128][256]
    const float* __restrict__ scs, const float* __restrict__ shs,
    const float* __restrict__ asrc, const float* __restrict__ adst,
    const float* __restrict__ wq,
    float* __restrict__ ad_, uint2* __restrict__ pack)
{
    __shared__ _Float16 ys[64][136];
    __shared__ _Float16 mid[64][264];
    const int n0 = blockIdx.x * 64;
    const int t = threadIdx.x;
    const int l = t & 63, w = t >> 6;
    const int lc = l & 15, kq = (l >> 4) * 8, lr = (l >> 4) * 4;
    const int m0w = (w & 1) * 32;          // 2 row-tiles per wave
    const f32x4 fzero = {0.f, 0.f, 0.f, 0.f};

    // ---- phase 1: per head, mid[:, h*64..] = ELU(BN1(y_h @ W1_h)) ----
    const int c0w = (w >> 1) * 32;         // 2 col-tiles per wave (within head)
    for (int h = 0; h < 4; ++h) {
        if (h) __syncthreads();
#pragma unroll
        for (int i = 0; i < 4; ++i) {
            const int f = i * 2048 + t * 8;
            const int m = f >> 7, k8 = f & 127;
            half8 v = {};
            if (n0 + m < NN)
                v = *(const half8*)&y[(unsigned)(n0 + m) * 512u + (unsigned)h * 128u + k8];
            *(half8*)&ys[m][k8] = v;
        }
        __syncthreads();

        f32x4 acc[2][2];
        acc[0][0] = fzero; acc[0][1] = fzero; acc[1][0] = fzero; acc[1][1] = fzero;
#pragma unroll
        for (int ks = 0; ks < 4; ++ks) {
            const int k0 = ks * 32 + kq;
            const half8 a0 = *(const half8*)&ys[m0w + lc][k0];
            const half8 a1 = *(const half8*)&ys[m0w + 16 + lc][k0];
            const half8 b0 = *(const half8*)&wt1[(unsigned)(h * 64 + c0w + lc) * 128u + k0];
            const half8 b1 = *(const half8*)&wt1[(unsigned)(h * 64 + c0w + 16 + lc) * 128u + k0];
            acc[0][0] = __builtin_amdgcn_mfma_f32_16x16x32_f16(a0, b0, acc[0][0], 0, 0, 0);
            acc[0][1] = __builtin_amdgcn_mfma_f32_16x16x32_f16(a0, b1, acc[0][1], 0, 0, 0);
            acc[1][0] = __builtin_amdgcn_mfma_f32_16x16x32_f16(a1, b0, acc[1][0], 0, 0, 0);
            acc[1][1] = __builtin_amdgcn_mfma_f32_16x16x32_f16(a1, b1, acc[1][1], 0, 0, 0);
        }
        // BN1 + ELU -> mid
#pragma unroll
        for (int c = 0; c < 2; ++c) {
            const int col = h * 64 + c0w + c * 16 + lc;
            const float scv = scs[col], shv = shs[col];
#pragma unroll
            for (int r = 0; r < 2; ++r) {
#pragma unroll
                for (int i = 0; i < 4; ++i) {
                    float e = fmaf(acc[r][c][i], scv, shv);
                    e = e > 0.f ? e : __expf(e) - 1.f;
                    mid[m0w + r * 16 + lr + i][col] = (_Float16)e;
                }
            }
        }
    }
    __syncthreads();

    // ---- phase 2: gemm2 K=256 from mid; wave head = w>>1, cols c20..c20+63 ----
    const int c20 = (w >> 1) * 64;
    f32x4 acc2[2][4];
#pragma unroll
    for (int r = 0; r < 2; ++r)
#pragma unroll
        for (int c = 0; c < 4; ++c) acc2[r][c] = fzero;
#pragma unroll
    for (int ks = 0; ks < 8; ++ks) {
        const int k0 = ks * 32 + kq;
        const half8 a0 = *(const half8*)&mid[m0w + lc][k0];
        const half8 a1 = *(const half8*)&mid[m0w + 16 + lc][k0];
#pragma unroll
        for (int c = 0; c < 4; ++c) {
            const half8 b = *(const half8*)&wt2[(unsigned)(c20 + c * 16 + lc) * 256u + k0];
            acc2[0][c] = __builtin_amdgcn_mfma_f32_16x16x32_f16(a0, b, acc2[0][c], 0, 0, 0);
            acc2[1][c] = __builtin_amdgcn_mfma_f32_16x16x32_f16(a1, b, acc2[1][c], 0, 0, 0);
        }
    }
    const int head = w >> 1;
    float awv[4], dwv[4], wq0[4], wq1[4];
#pragma unroll
    for (int c = 0; c < 4; ++c) {
        const int j = c20 + c * 16 + lc;
        const int cl = j & 63;
        awv[c] = asrc[j];
        dwv[c] = adst[j];
        wq0[c] = wq[cl * 2 + 0];
        wq1[c] = wq[cl * 2 + 1];
    }
#pragma unroll
    for (int r = 0; r < 2; ++r) {
#pragma unroll
        for (int i = 0; i < 4; ++i) {
            float s = 0.f, d = 0.f, q0 = 0.f, q1 = 0.f;
#pragma unroll
            for (int c = 0; c < 4; ++c) {
                s = fmaf(acc2[r][c][i], awv[c], s);
                d = fmaf(acc2[r][c][i], dwv[c], d);
                q0 = fmaf(acc2[r][c][i], wq0[c], q0);
                q1 = fmaf(acc2[r][c][i], wq1[c], q1);
            }
            s = gsum16(s); d = gsum16(d); q0 = gsum16(q0); q1 = gsum16(q1);
            const int rg = n0 + m0w + r * 16 + lr + i;
            if (lc == 0 && rg < NN) {
                ad_[rg * 2 + head] = d;
                uint2 u;
                u.x = __float_as_uint(s);
                u.y = packh2(q0, q1);
                pack[rg * 2 + head] = u;
            }
        }
    }
}

// ====== layer-2: single-pass softmax; one 16B record gather per edge ======
__global__ __launch_bounds__(256) void k_agg2q(
    const int* __restrict__ rowptr, const int* __restrict__ srcs,
    const uint4* __restrict__ pack, const float* __restrict__ ad_,
    const float* __restrict__ cst, float* __restrict__ out)
{
    const int d = blockIdx.x * 16 + (threadIdx.x >> 4);
    if (d >= NN) return;
    const int il = threadIdx.x & 15;
    const int r0 = rowptr[d], r1 = rowptr[d + 1];
    const float2 adv = *(const float2*)&ad_[d * 2];

    float den0 = 0.f, den1 = 0.f;
    float qa00 = 0.f, qa01 = 0.f, qa10 = 0.f, qa11 = 0.f;
    for (int k = r0 + il; k < r1; k += 16) {
        const unsigned s = (unsigned)srcs[k];
        const uint4 rec = pack[s];
        const float a0 = __uint_as_float(rec.x);
        const float a1 = __uint_as_float(rec.z);
        const float2 q0 = __half22float2(*reinterpret_cast<const __half2*>(&rec.y));
        const float2 q1 = __half22float2(*reinterpret_cast<const __half2*>(&rec.w));
        const float p0 = __expf(lrelu(a0 + adv.x));
        const float p1 = __expf(lrelu(a1 + adv.y));
        den0 += p0; den1 += p1;
        qa00 = fmaf(p0, q0.x, qa00); qa01 = fmaf(p0, q0.y, qa01);
        qa10 = fmaf(p1, q1.x, qa10); qa11 = fmaf(p1, q1.y, qa11);
    }
    den0 = gsum16(den0); den1 = gsum16(den1);
    qa00 = gsum16(qa00); qa01 = gsum16(qa01);
    qa10 = gsum16(qa10); qa11 = gsum16(qa11);
    if (il == 0) {
        const float i0 = 1.f / (den0 + 1e-16f);
        const float i1 = 1.f / (den1 + 1e-16f);
        out[d * 2 + 0] = cst[0] + 0.5f * (qa00 * i0 + qa10 * i1);
        out[d * 2 + 1] = cst[1] + 0.5f * (qa01 * i0 + qa11 * i1);
    }
}

extern "C" void kernel_launch(void* const* d_in, const int* in_sizes, int n_in,
                              void* d_out, int out_size, void* d_ws, size_t ws_size,
                              hipStream_t stream) {
    const float* x      = (const float*)d_in[0];
    const int*   ei     = (const int*)d_in[1];
    const float* w1     = (const float*)d_in[2];
    const float* a_src1 = (const float*)d_in[3];
    const float* a_dst1 = (const float*)d_in[4];
    const float* b1     = (const float*)d_in[5];
    const float* g1     = (const float*)d_in[6];
    const float* be1    = (const float*)d_in[7];
    const float* m1     = (const float*)d_in[8];
    const float* v1     = (const float*)d_in[9];
    const float* w2     = (const float*)d_in[10];
    const float* a_src2 = (const float*)d_in[11];
    const float* a_dst2 = (const float*)d_in[12];
    const float* b2     = (const float*)d_in[13];
    const float* g2     = (const float*)d_in[14];
    const float* be2    = (const float*)d_in[15];
    const float* m2     = (const float*)d_in[16];
    const float* v2     = (const float*)d_in[17];
    const float* wc     = (const float*)d_in[18];
    const float* bc     = (const float*)d_in[19];
    float* out = (float*)d_out;

    float* ws = (float*)d_ws;
    _Float16* xh = (_Float16*)ws;                      // NN*128 h  (NN*64 fl)
    _Float16* y  = (_Float16*)(ws + (size_t)NN * 64);  // NN*512 h  (NN*256 fl)
    float* C = ws + (size_t)NN * 320;

    float* as1 = C;                        // NN*4
    float* ad1 = C + (size_t)NN * 4;       // NN*4
    float* ad2 = C + (size_t)NN * 8;       // NN*2
    float* packf = C + (size_t)NN * 10;    // NN*4 (uint2 x2 per node)
    float* scs = C + (size_t)NN * 14;      // 256
    float* shs = scs + 256;                // 256
    float* wq  = shs + 256;                // 128
    float* cst = wq + 128;                 // 64
    float* va  = cst + 64;                 // 512
    float* vd  = va + 512;                 // 512
    float* wbase = vd + 512;
    _Float16* wt1 = (_Float16*)wbase;      // 32768 h (16384 fl)
    _Float16* wt2 = wt1 + 32768;           // 32768 h
    int* counts = (int*)(wbase + 32768);   // NN (reused as cursor)
    int* rowptr = counts + NN;             // NN+1
    int* bsum   = rowptr + NN + 63;        // 512
    int* srcs   = bsum + 512;              // ETOT

    // ---- counts zero + combined prep/hist ----
    hipMemsetAsync(counts, 0, (size_t)NN * sizeof(int), stream);
    k_preph<<<259 + HISTBLK, 256, 0, stream>>>(
        b1, g1, be1, m1, v1, b2, g2, be2, m2, v2, wc, bc, w1, w2,
        a_src1, a_dst1, ei, scs, shs, wq, cst, va, vd, wt1, wt2, counts);

    // ---- CSR scans ----
    k_scan_bsum<<<NBLK, 256, 0, stream>>>(counts, bsum);
    k_scan_finaltop<<<NBLK, 256, 0, stream>>>(counts, bsum, rowptr, srcs, counts);

    // ---- merged scatter + xcvt (independent; overlap in one dispatch) ----
    k_scx<<<SCTBLK + XCVTBLK, 256, 0, stream>>>(ei, srcs, counts,
                                                x, va, vd, xh, as1, ad1);

    // ---- layer 1 aggregation ----
    k_agg1x<<<(NN + 3) / 4, 256, 0, stream>>>(rowptr, srcs, xh, as1, ad1, y);

    // ---- fused BD-GEMM + GEMM2 ----
    k_l2fuse<<<(NN + 63) / 64, 256, 0, stream>>>(y, wt1, wt2, scs, shs,
                                                 a_src2, a_dst2, wq,
                                                 ad2, (uint2*)packf);

    // ---- layer 2 edge pass ----
    k_agg2q<<<(NN + 15) / 16, 256, 0, stream>>>(rowptr, srcs, (const uint4*)packf,
                                                ad2, cst, out);
}